// Round 8
// baseline (72.429 us; speedup 1.0000x reference)
//
#include <hip/hip_runtime.h>
#include <hip/hip_bf16.h>

#define EPS 1e-5f
#define SLOPE 0.01f

typedef __attribute__((ext_vector_type(8))) short bfrag8;   // 8 bf16 (4 VGPRs)
typedef __attribute__((ext_vector_type(4))) float f32x4;

#define AS1 __attribute__((address_space(1)))
#define AS3 __attribute__((address_space(3)))

// ---- workspace byte offsets ----
#define WS_SIM_OFF   0u          // [1024][16] f32 (fully written by sim_kernel)
#define WS_S_OFF     65536u      // [1024][16] f32
#define WS_WVS_OFF   131072u     // [2048][16] f32, transposed [c][n]
#define WS_BVS_OFF   262144u     // [16] f32
#define WS_OUT_OFF   262208u     // [1024][2048] f32 = 8,388,608 B (q cols 0-1023, k cols 1024-2047)
#define WS_AIMG_OFF  8650816u    // bf16 A image, swizzle-baked: [src2][mt16][kt32][p512]x16B = 16,777,216 B
#define WS_BIMG_OFF  25428032u   // bf16 B image, swizzle-baked: [nt32][kt32][p512]x16B = 8,388,608 B

// round-to-nearest-even fp32 -> bf16
__device__ __forceinline__ unsigned short f2bf(float f) {
    union { float f; unsigned int u; } x; x.f = f;
    unsigned int r = (x.u + 0x7FFFu + ((x.u >> 16) & 1u)) >> 16;
    return (unsigned short)r;
}
__device__ __forceinline__ uint4 pack8(const float4& a, const float4& b) {
    uint4 r;
    r.x = (unsigned)f2bf(a.x) | ((unsigned)f2bf(a.y) << 16);
    r.y = (unsigned)f2bf(a.z) | ((unsigned)f2bf(a.w) << 16);
    r.z = (unsigned)f2bf(b.x) | ((unsigned)f2bf(b.y) << 16);
    r.w = (unsigned)f2bf(b.z) | ((unsigned)f2bf(b.w) << 16);
    return r;
}

// ---------------- kernel 0: prep — swizzle-baked bf16 images + WvS + bvS ----------------
// Image granule p (16 B) of a 64x64 k-tile: row = p>>3, slot g = p&7 holds k-granule
// gk = g ^ (row&7)  (T2 XOR swizzle baked at build; ds_read applies the same XOR).
#define PREP_A    524288                    // 2*16*32*512
#define PREP_B2   (PREP_A + 524288)         // 32*32*512
#define PREP_WVSE (PREP_B2 + 32768)
#define PREP_END  (PREP_WVSE + 16)

__global__ __launch_bounds__(256) void prep_kernel(
        const float* __restrict__ qin, const float* __restrict__ kvin,
        const float* __restrict__ Wq, const float* __restrict__ Wkv,
        const float* __restrict__ bkv, unsigned char* __restrict__ ws) {
    int gid = blockIdx.x * 256 + threadIdx.x;
    if (gid < PREP_A) {
        int p  = gid & 511;
        int kt = (gid >> 9) & 31;
        int mt = (gid >> 14) & 15;
        int s2 = gid >> 18;                    // 0 = q_input, 1 = kv_input
        int rit = p >> 3;                      // row in tile 0..63
        int gk = (p & 7) ^ (rit & 7);
        int row = mt * 64 + rit;
        int k = kt * 64 + gk * 8;
        const float* src = (s2 ? kvin : qin) + (size_t)row * 2048 + k;
        float4 v0 = *(const float4*)src;
        float4 v1 = *(const float4*)(src + 4);
        *(uint4*)(ws + WS_AIMG_OFF + (size_t)gid * 16) = pack8(v0, v1);
    } else if (gid < PREP_B2) {
        int g2 = gid - PREP_A;
        int p  = g2 & 511;
        int kt = (g2 >> 9) & 31;
        int nt = g2 >> 14;                     // 0..31
        int cit = p >> 3;
        int gk = (p & 7) ^ (cit & 7);
        int col = nt * 64 + cit;               // global output col
        int k = kt * 64 + gk * 8;
        const float* wrow;
        if (col < 1024) wrow = Wq + (size_t)col * 2048;
        else {
            int c2 = col - 1024;
            wrow = Wkv + (size_t)(((c2 >> 6) << 7) + (c2 & 63)) * 2048;
        }
        float4 v0 = *(const float4*)(wrow + k);
        float4 v1 = *(const float4*)(wrow + k + 4);
        *(uint4*)(ws + WS_BIMG_OFF + (size_t)g2 * 16) = pack8(v0, v1);
    } else if (gid < PREP_WVSE) {
        int g2 = gid - PREP_B2;
        int n = g2 >> 11, c = g2 & 2047;
        const float* base = Wkv + (size_t)(n * 128 + 64) * 2048 + c;
        float s = 0.f;
        #pragma unroll 8
        for (int d = 0; d < 64; ++d) s += base[(size_t)d * 2048];
        ((float*)(ws + WS_WVS_OFF))[c * 16 + n] = s;
    } else if (gid < PREP_END) {
        int n = gid - PREP_WVSE;
        float b = 0.f;
        #pragma unroll
        for (int d = 0; d < 64; ++d) b += bkv[n * 128 + 64 + d];
        ((float*)(ws + WS_BVS_OFF))[n] = b;
    }
}

// ---------------- kernel 1: Out = [q|k] projection GEMM (m97 2-barrier structure) ----------------
// grid (x=ntile 32, y=mtile 16) = 512 blocks (2 blocks/CU), 256 thr = 4 waves.
// Wave (wr=w>>1, wc=w&1) owns a 32x32 C sub-tile. BK=64, double-buffered LDS,
// global_load_lds width-16 from swizzle-baked images (linear dest, rule 21).
__global__ __launch_bounds__(256) void gemm_qk_kernel(unsigned char* __restrict__ ws) {
    __shared__ alignas(16) unsigned short LA[2][4096];   // 2 x 8 KB, [row64][128B swizzled]
    __shared__ alignas(16) unsigned short LB[2][4096];

    const int t = threadIdx.x;
    const int w = t >> 6, l = t & 63;
    const int nt = blockIdx.x, mt = blockIdx.y;
    const int wr = w >> 1, wc = w & 1;
    const int lrow = l & 15, lhi = l >> 4;

    const unsigned char* aBase = ws + WS_AIMG_OFF
        + (size_t)((nt >= 16) ? 4194304u : 0u) + (size_t)mt * 262144u;
    const unsigned char* bBase = ws + WS_BIMG_OFF + (size_t)nt * 262144u;
    float* Out = (float*)(ws + WS_OUT_OFF);

    // loop-invariant swizzled ds_read byte offsets (T2: gk slot = gk ^ (row&7))
    int offA[2][2], offB[2][2];
    #pragma unroll
    for (int ks = 0; ks < 2; ++ks)
        #pragma unroll
        for (int i = 0; i < 2; ++i) {
            int rA = wr * 32 + i * 16 + lrow;
            int rB = wc * 32 + i * 16 + lrow;
            offA[ks][i] = rA * 128 + (((ks * 4 + lhi) ^ (rA & 7)) << 4);
            offB[ks][i] = rB * 128 + (((ks * 4 + lhi) ^ (rB & 7)) << 4);
        }

    f32x4 acc00 = (f32x4)0.f, acc01 = (f32x4)0.f, acc10 = (f32x4)0.f, acc11 = (f32x4)0.f;

#define STAGE(kt_, buf_) do {                                                        \
    const unsigned char* _as = aBase + (size_t)(kt_) * 8192;                         \
    const unsigned char* _bs = bBase + (size_t)(kt_) * 8192;                         \
    unsigned char* _ad = ((unsigned char*)&LA[0][0]) + (buf_) * 8192;                \
    unsigned char* _bd = ((unsigned char*)&LB[0][0]) + (buf_) * 8192;                \
    _Pragma("unroll")                                                                \
    for (int _j = 0; _j < 2; ++_j) {                                                 \
        int _p = _j * 256 + t;                                                       \
        __builtin_amdgcn_global_load_lds(                                            \
            (const AS1 unsigned int*)(const void*)(_as + _p * 16),                   \
            (AS3 unsigned int*)(void*)(_ad + _p * 16), 16, 0, 0);                    \
        __builtin_amdgcn_global_load_lds(                                            \
            (const AS1 unsigned int*)(const void*)(_bs + _p * 16),                   \
            (AS3 unsigned int*)(void*)(_bd + _p * 16), 16, 0, 0);                    \
    } } while (0)

    // prologue
    STAGE(0, 0);
    __syncthreads();

    for (int kt = 0; kt < 32; ++kt) {
        const int cur = kt & 1;
        if (kt < 31) STAGE(kt + 1, cur ^ 1);
        const char* la = (const char*)&LA[0][0] + cur * 8192;
        const char* lb = (const char*)&LB[0][0] + cur * 8192;
        bfrag8 fa00 = *(const bfrag8*)(la + offA[0][0]);
        bfrag8 fa01 = *(const bfrag8*)(la + offA[0][1]);
        bfrag8 fa10 = *(const bfrag8*)(la + offA[1][0]);
        bfrag8 fa11 = *(const bfrag8*)(la + offA[1][1]);
        bfrag8 fb00 = *(const bfrag8*)(lb + offB[0][0]);
        bfrag8 fb01 = *(const bfrag8*)(lb + offB[0][1]);
        bfrag8 fb10 = *(const bfrag8*)(lb + offB[1][0]);
        bfrag8 fb11 = *(const bfrag8*)(lb + offB[1][1]);
        acc00 = __builtin_amdgcn_mfma_f32_16x16x32_bf16(fa00, fb00, acc00, 0, 0, 0);
        acc01 = __builtin_amdgcn_mfma_f32_16x16x32_bf16(fa00, fb01, acc01, 0, 0, 0);
        acc10 = __builtin_amdgcn_mfma_f32_16x16x32_bf16(fa01, fb00, acc10, 0, 0, 0);
        acc11 = __builtin_amdgcn_mfma_f32_16x16x32_bf16(fa01, fb01, acc11, 0, 0, 0);
        acc00 = __builtin_amdgcn_mfma_f32_16x16x32_bf16(fa10, fb10, acc00, 0, 0, 0);
        acc01 = __builtin_amdgcn_mfma_f32_16x16x32_bf16(fa10, fb11, acc01, 0, 0, 0);
        acc10 = __builtin_amdgcn_mfma_f32_16x16x32_bf16(fa11, fb10, acc10, 0, 0, 0);
        acc11 = __builtin_amdgcn_mfma_f32_16x16x32_bf16(fa11, fb11, acc11, 0, 0, 0);
        __syncthreads();   // vmcnt(0)+lgkmcnt(0)+barrier: next buffer ready, cur reusable
    }
#undef STAGE

    // epilogue: store C fp32 (bias applied exactly in sim_kernel)
    f32x4 acc[2][2] = {{acc00, acc01}, {acc10, acc11}};
    #pragma unroll
    for (int mi = 0; mi < 2; ++mi)
        #pragma unroll
        for (int ni = 0; ni < 2; ++ni) {
            int col = nt * 64 + wc * 32 + ni * 16 + lrow;
            #pragma unroll
            for (int r = 0; r < 4; ++r) {
                int row = mt * 64 + wr * 32 + mi * 16 + lhi * 4 + r;
                Out[(size_t)row * 2048 + col] = acc[mi][ni][r];
            }
        }
}

// ---------------- kernel 2: sim[b,h] = (q+bq)·(k+bk) per head (exact fp32 bias) ----------------
__global__ __launch_bounds__(256) void sim_kernel(
        const float* __restrict__ bq, const float* __restrict__ bkv,
        unsigned char* __restrict__ ws) {
    int b = blockIdx.x, t = threadIdx.x;
    int w = t >> 6, d = t & 63;
    const float* orow = (const float*)(ws + WS_OUT_OFF) + (size_t)b * 2048;
    float* sim = (float*)(ws + WS_SIM_OFF);
    #pragma unroll
    for (int hh = 0; hh < 4; ++hh) {
        int h = w * 4 + hh;
        float qv = orow[h * 64 + d]        + bq[h * 64 + d];
        float kv = orow[1024 + h * 64 + d] + bkv[h * 128 + d];
        float p = qv * kv;
        p += __shfl_xor(p, 1);  p += __shfl_xor(p, 2);
        p += __shfl_xor(p, 4);  p += __shfl_xor(p, 8);
        p += __shfl_xor(p, 16); p += __shfl_xor(p, 32);
        if (d == 0) sim[b * 16 + h] = p;
    }
}

// ---------------- kernel 3: S[b][n] = kv_input[b]·WvS[:,n] + bvS[n] (fp32) ----------------
__global__ __launch_bounds__(256) void s_kernel(
        const float* __restrict__ kvin, unsigned char* __restrict__ ws) {
    int b = blockIdx.x, t = threadIdx.x;
    int w = t >> 6, l = t & 63;
    __shared__ float SW[4][16];
    int n = t & 15, g = t >> 4;
    const float* kvrow = kvin + (size_t)b * 2048;
    const float* wv = (const float*)(ws + WS_WVS_OFF);
    float p = 0.f;
    #pragma unroll 4
    for (int tt = 0; tt < 128; ++tt) {
        int c = g + (tt << 4);
        p = fmaf(kvrow[c], wv[c * 16 + n], p);
    }
    p += __shfl_xor(p, 16);
    p += __shfl_xor(p, 32);
    if (l < 16) SW[w][n] = p;
    __syncthreads();
    if (t < 16) {
        float sv = SW[0][t] + SW[1][t] + SW[2][t] + SW[3][t]
                 + ((const float*)(ws + WS_BVS_OFF))[t];
        ((float*)(ws + WS_S_OFF))[b * 16 + t] = sv;
    }
}

// ---------------- kernel 4: softmax, A-reduce, pooled, leaky, batchnorm, output ----------------
__global__ __launch_bounds__(1024) void final_kernel(
        const float* __restrict__ bn_w, const float* __restrict__ bn_b,
        const float* __restrict__ Wo, const float* __restrict__ bo,
        const unsigned char* __restrict__ ws, float* __restrict__ out) {
    int t = threadIdx.x;
    int w = t >> 6;
    int l = t & 63;
    __shared__ float Aw[16][16];
    __shared__ float Af[4][16];
    __shared__ float SWs[16][8];
    __shared__ float FS[8];
    __shared__ float sc[4], sh[4];

    float a16[16];
    {
        const float* srow = (const float*)(ws + WS_SIM_OFF) + (size_t)t * 16;
        float4 v0 = *(const float4*)(srow + 0);
        float4 v1 = *(const float4*)(srow + 4);
        float4 v2 = *(const float4*)(srow + 8);
        float4 v3 = *(const float4*)(srow + 12);
        a16[0]=v0.x; a16[1]=v0.y; a16[2]=v0.z; a16[3]=v0.w;
        a16[4]=v1.x; a16[5]=v1.y; a16[6]=v1.z; a16[7]=v1.w;
        a16[8]=v2.x; a16[9]=v2.y; a16[10]=v2.z; a16[11]=v2.w;
        a16[12]=v3.x; a16[13]=v3.y; a16[14]=v3.z; a16[15]=v3.w;
        float m = a16[0];
        #pragma unroll
        for (int n = 1; n < 16; ++n) m = fmaxf(m, a16[n]);
        float den = 0.f;
        #pragma unroll
        for (int n = 0; n < 16; ++n) { a16[n] = expf(a16[n] - m); den += a16[n]; }
        float inv = 1.f / den;
        #pragma unroll
        for (int n = 0; n < 16; ++n) a16[n] *= inv;
    }
    #pragma unroll
    for (int n = 0; n < 16; ++n) {
        float p = a16[n];
        p += __shfl_xor(p, 1);  p += __shfl_xor(p, 2);
        p += __shfl_xor(p, 4);  p += __shfl_xor(p, 8);
        p += __shfl_xor(p, 16); p += __shfl_xor(p, 32);
        a16[n] = p;
    }
    if (l == 0) {
        #pragma unroll
        for (int n = 0; n < 16; ++n) Aw[w][n] = a16[n];
    }
    __syncthreads();
    if (t < 64) {
        int f = t >> 4, n = t & 15;
        Af[f][n] = Aw[4*f][n] + Aw[4*f+1][n] + Aw[4*f+2][n] + Aw[4*f+3][n];
    }
    __syncthreads();

    float sv[16];
    {
        const float* srow = (const float*)(ws + WS_S_OFF) + (size_t)t * 16;
        float4 v0 = *(const float4*)(srow + 0);
        float4 v1 = *(const float4*)(srow + 4);
        float4 v2 = *(const float4*)(srow + 8);
        float4 v3 = *(const float4*)(srow + 12);
        sv[0]=v0.x; sv[1]=v0.y; sv[2]=v0.z; sv[3]=v0.w;
        sv[4]=v1.x; sv[5]=v1.y; sv[6]=v1.z; sv[7]=v1.w;
        sv[8]=v2.x; sv[9]=v2.y; sv[10]=v2.z; sv[11]=v2.w;
        sv[12]=v3.x; sv[13]=v3.y; sv[14]=v3.z; sv[15]=v3.w;
    }
    float x[4];
    #pragma unroll
    for (int f = 0; f < 4; ++f) {
        float p = 0.f;
        #pragma unroll
        for (int n = 0; n < 16; ++n) p = fmaf(Af[f][n], sv[n], p);
        p *= (1.f / 16384.f);
        x[f] = (p >= 0.f) ? p : SLOPE * p;
    }

    float st[8];
    #pragma unroll
    for (int f = 0; f < 4; ++f) { st[f] = x[f]; st[4 + f] = x[f] * x[f]; }
    #pragma unroll
    for (int j = 0; j < 8; ++j) {
        float p = st[j];
        p += __shfl_xor(p, 1);  p += __shfl_xor(p, 2);
        p += __shfl_xor(p, 4);  p += __shfl_xor(p, 8);
        p += __shfl_xor(p, 16); p += __shfl_xor(p, 32);
        st[j] = p;
    }
    if (l == 0) {
        #pragma unroll
        for (int j = 0; j < 8; ++j) SWs[w][j] = st[j];
    }
    __syncthreads();
    if (t < 8) {
        float p = 0.f;
        #pragma unroll
        for (int ww = 0; ww < 16; ++ww) p += SWs[ww][t];
        FS[t] = p;
    }
    __syncthreads();
    if (t < 4) {
        float mean = FS[t] * (1.f / 1024.f);
        float var  = FS[4 + t] * (1.f / 1024.f) - mean * mean;
        float s = bn_w[t] / sqrtf(var + EPS);
        sc[t] = s;
        sh[t] = bn_b[t] - mean * s;
    }
    __syncthreads();

    float o0 = bo[0], o1 = bo[1];
    #pragma unroll
    for (int f = 0; f < 4; ++f) {
        float xh = x[f] * sc[f] + sh[f];
        o0 = fmaf(xh, Wo[f], o0);
        o1 = fmaf(xh, Wo[4 + f], o1);
    }
    *(float2*)(out + (size_t)t * 2) = make_float2(o0, o1);
}

// ---------------- launch ----------------
extern "C" void kernel_launch(void* const* d_in, const int* in_sizes, int n_in,
                              void* d_out, int out_size, void* d_ws, size_t ws_size,
                              hipStream_t stream) {
    const float* q_input  = (const float*)d_in[0];
    const float* kv_input = (const float*)d_in[1];
    const float* Wq   = (const float*)d_in[2];
    const float* bq   = (const float*)d_in[3];
    const float* Wkv  = (const float*)d_in[4];
    const float* bkv  = (const float*)d_in[5];
    const float* bn_w = (const float*)d_in[6];
    const float* bn_b = (const float*)d_in[7];
    const float* Wo   = (const float*)d_in[8];
    const float* bo   = (const float*)d_in[9];
    float* out = (float*)d_out;
    unsigned char* ws = (unsigned char*)d_ws;

    hipLaunchKernelGGL(prep_kernel, dim3((PREP_END + 255) / 256), dim3(256), 0, stream,
                       q_input, kv_input, Wq, Wkv, bkv, ws);
    hipLaunchKernelGGL(gemm_qk_kernel, dim3(32, 16), dim3(256), 0, stream, ws);
    hipLaunchKernelGGL(sim_kernel, dim3(1024), dim3(256), 0, stream, bq, bkv, ws);
    hipLaunchKernelGGL(s_kernel, dim3(1024), dim3(256), 0, stream, kv_input, ws);
    hipLaunchKernelGGL(final_kernel, dim3(1), dim3(1024), 0, stream,
                       bn_w, bn_b, Wo, bo, ws, out);
}

// Round 9
// 62.939 us; speedup vs baseline: 1.1508x; 1.1508x over previous
//
#include <hip/hip_runtime.h>
#include <hip/hip_bf16.h>

#define EPS 1e-5f
#define SLOPE 0.01f

typedef __attribute__((ext_vector_type(8))) short bfrag8;   // 8 bf16 (4 VGPRs)
typedef __attribute__((ext_vector_type(4))) float f32x4;

#define AS1 __attribute__((address_space(1)))
#define AS3 __attribute__((address_space(3)))

// ---- workspace byte offsets ----
#define WS_SIM_OFF   0u          // [1024][16] f32 (fully written by sim_s_kernel)
#define WS_S_OFF     65536u      // [1024][16] f32
#define WS_WVS_OFF   131072u     // [2048][16] f32, transposed [c][n]
#define WS_BVS_OFF   262144u     // [16] f32
#define WS_OUT_OFF   262208u     // [1024][2048] f32 (q cols 0-1023, k cols 1024-2047)
#define WS_AIMG_OFF  8650816u    // bf16 A image, swizzle-baked: [src2][mt16][kt32][p512]x16B = 8,388,608 B
#define WS_BIMG_OFF  25428032u   // bf16 B image, swizzle-baked: [nt32][kt32][p512]x16B = 8,388,608 B

// round-to-nearest-even fp32 -> bf16
__device__ __forceinline__ unsigned short f2bf(float f) {
    union { float f; unsigned int u; } x; x.f = f;
    unsigned int r = (x.u + 0x7FFFu + ((x.u >> 16) & 1u)) >> 16;
    return (unsigned short)r;
}
__device__ __forceinline__ uint4 pack8(const float4& a, const float4& b) {
    uint4 r;
    r.x = (unsigned)f2bf(a.x) | ((unsigned)f2bf(a.y) << 16);
    r.y = (unsigned)f2bf(a.z) | ((unsigned)f2bf(a.w) << 16);
    r.z = (unsigned)f2bf(b.x) | ((unsigned)f2bf(b.y) << 16);
    r.w = (unsigned)f2bf(b.z) | ((unsigned)f2bf(b.w) << 16);
    return r;
}

// ---------------- kernel 0: prep — swizzle-baked bf16 images + WvS + bvS ----------------
// Image granule p (16 B) of a 64x64 k-tile: row = p>>3, slot g = p&7 holds k-granule
// gk = g ^ (row&7)  (T2 XOR swizzle baked at build; ds_read applies the same XOR).
#define PREP_A    524288                    // 2*16*32*512
#define PREP_B2   (PREP_A + 524288)         // 32*32*512
#define PREP_WVSE (PREP_B2 + 32768)
#define PREP_END  (PREP_WVSE + 16)

__global__ __launch_bounds__(256) void prep_kernel(
        const float* __restrict__ qin, const float* __restrict__ kvin,
        const float* __restrict__ Wq, const float* __restrict__ Wkv,
        const float* __restrict__ bkv, unsigned char* __restrict__ ws) {
    int gid = blockIdx.x * 256 + threadIdx.x;
    if (gid < PREP_A) {
        int p  = gid & 511;
        int kt = (gid >> 9) & 31;
        int mt = (gid >> 14) & 15;
        int s2 = gid >> 18;                    // 0 = q_input, 1 = kv_input
        int rit = p >> 3;                      // row in tile 0..63
        int gk = (p & 7) ^ (rit & 7);
        int row = mt * 64 + rit;
        int k = kt * 64 + gk * 8;
        const float* src = (s2 ? kvin : qin) + (size_t)row * 2048 + k;
        float4 v0 = *(const float4*)src;
        float4 v1 = *(const float4*)(src + 4);
        *(uint4*)(ws + WS_AIMG_OFF + (size_t)gid * 16) = pack8(v0, v1);
    } else if (gid < PREP_B2) {
        int g2 = gid - PREP_A;
        int p  = g2 & 511;
        int kt = (g2 >> 9) & 31;
        int nt = g2 >> 14;                     // 0..31
        int cit = p >> 3;
        int gk = (p & 7) ^ (cit & 7);
        int col = nt * 64 + cit;               // global output col
        int k = kt * 64 + gk * 8;
        const float* wrow;
        if (col < 1024) wrow = Wq + (size_t)col * 2048;
        else {
            int c2 = col - 1024;
            wrow = Wkv + (size_t)(((c2 >> 6) << 7) + (c2 & 63)) * 2048;
        }
        float4 v0 = *(const float4*)(wrow + k);
        float4 v1 = *(const float4*)(wrow + k + 4);
        *(uint4*)(ws + WS_BIMG_OFF + (size_t)g2 * 16) = pack8(v0, v1);
    } else if (gid < PREP_WVSE) {
        int g2 = gid - PREP_B2;
        int n = g2 >> 11, c = g2 & 2047;
        const float* base = Wkv + (size_t)(n * 128 + 64) * 2048 + c;
        float s = 0.f;
        #pragma unroll 8
        for (int d = 0; d < 64; ++d) s += base[(size_t)d * 2048];
        ((float*)(ws + WS_WVS_OFF))[c * 16 + n] = s;
    } else if (gid < PREP_END) {
        int n = gid - PREP_WVSE;
        float b = 0.f;
        #pragma unroll
        for (int d = 0; d < 64; ++d) b += bkv[n * 128 + 64 + d];
        ((float*)(ws + WS_BVS_OFF))[n] = b;
    }
}

// ---------------- kernel 1: Out = [q|k] projection GEMM — T3/T4 counted-vmcnt pipeline ----------------
// grid (x=ntile 32, y=mtile 16) = 512 blocks (2/CU), 256 thr = 4 waves.
// 3-buffer LDS (48 KB), depth-2 prefetch: per iter {COMPUTE(cur); STAGE(kt+2->nxt);
// s_waitcnt vmcnt(4); s_barrier} — newest stage's 4 DMAs stay in flight across the
// barrier (never drain to 0 in steady state). WAR-safe: stage(kt+2) overwrites the
// buffer last read at kt-1, behind the end-of-(kt-1) barrier.
__global__ __launch_bounds__(256, 2) void gemm_qk_kernel(unsigned char* __restrict__ ws) {
    __shared__ alignas(16) unsigned short LA[3][4096];   // 3 x 8 KB
    __shared__ alignas(16) unsigned short LB[3][4096];

    const int t = threadIdx.x;
    const int w = t >> 6, l = t & 63;
    const int nt = blockIdx.x, mt = blockIdx.y;
    const int wr = w >> 1, wc = w & 1;
    const int lrow = l & 15, lhi = l >> 4;

    const unsigned char* aBase = ws + WS_AIMG_OFF
        + (size_t)((nt >= 16) ? 4194304u : 0u) + (size_t)mt * 262144u;
    const unsigned char* bBase = ws + WS_BIMG_OFF + (size_t)nt * 262144u;
    float* Out = (float*)(ws + WS_OUT_OFF);

    // loop-invariant swizzled ds_read byte offsets (T2: slot = kg ^ (row&7))
    int offA[2][2], offB[2][2];
    #pragma unroll
    for (int ks = 0; ks < 2; ++ks)
        #pragma unroll
        for (int i = 0; i < 2; ++i) {
            int rA = wr * 32 + i * 16 + lrow;
            int rB = wc * 32 + i * 16 + lrow;
            offA[ks][i] = rA * 128 + (((ks * 4 + lhi) ^ (rA & 7)) << 4);
            offB[ks][i] = rB * 128 + (((ks * 4 + lhi) ^ (rB & 7)) << 4);
        }

    f32x4 acc00 = (f32x4)0.f, acc01 = (f32x4)0.f, acc10 = (f32x4)0.f, acc11 = (f32x4)0.f;

#define STAGE(kt_, buf_) do {                                                        \
    const unsigned char* _as = aBase + (size_t)(kt_) * 8192;                         \
    const unsigned char* _bs = bBase + (size_t)(kt_) * 8192;                         \
    unsigned char* _ad = ((unsigned char*)&LA[0][0]) + (size_t)(buf_) * 8192;        \
    unsigned char* _bd = ((unsigned char*)&LB[0][0]) + (size_t)(buf_) * 8192;        \
    _Pragma("unroll")                                                                \
    for (int _j = 0; _j < 2; ++_j) {                                                 \
        int _p = _j * 256 + t;                                                       \
        __builtin_amdgcn_global_load_lds(                                            \
            (const AS1 unsigned int*)(const void*)(_as + _p * 16),                   \
            (AS3 unsigned int*)(void*)(_ad + _p * 16), 16, 0, 0);                    \
        __builtin_amdgcn_global_load_lds(                                            \
            (const AS1 unsigned int*)(const void*)(_bs + _p * 16),                   \
            (AS3 unsigned int*)(void*)(_bd + _p * 16), 16, 0, 0);                    \
    } } while (0)

    // ---- prologue: stage tiles 0,1; complete 0, leave 1 in flight ----
    STAGE(0, 0);
    STAGE(1, 1);
    asm volatile("s_waitcnt vmcnt(4)" ::: "memory");
    __builtin_amdgcn_sched_barrier(0);
    __builtin_amdgcn_s_barrier();
    __builtin_amdgcn_sched_barrier(0);

    int cur = 0, nxt = 2;
    for (int kt = 0; kt < 32; ++kt) {
        // ---- compute k-tile kt from buffer cur ----
        const char* la = (const char*)&LA[0][0] + cur * 8192;
        const char* lb = (const char*)&LB[0][0] + cur * 8192;
        bfrag8 fa00 = *(const bfrag8*)(la + offA[0][0]);
        bfrag8 fa01 = *(const bfrag8*)(la + offA[0][1]);
        bfrag8 fa10 = *(const bfrag8*)(la + offA[1][0]);
        bfrag8 fa11 = *(const bfrag8*)(la + offA[1][1]);
        bfrag8 fb00 = *(const bfrag8*)(lb + offB[0][0]);
        bfrag8 fb01 = *(const bfrag8*)(lb + offB[0][1]);
        bfrag8 fb10 = *(const bfrag8*)(lb + offB[1][0]);
        bfrag8 fb11 = *(const bfrag8*)(lb + offB[1][1]);
        acc00 = __builtin_amdgcn_mfma_f32_16x16x32_bf16(fa00, fb00, acc00, 0, 0, 0);
        acc01 = __builtin_amdgcn_mfma_f32_16x16x32_bf16(fa00, fb01, acc01, 0, 0, 0);
        acc10 = __builtin_amdgcn_mfma_f32_16x16x32_bf16(fa01, fb00, acc10, 0, 0, 0);
        acc11 = __builtin_amdgcn_mfma_f32_16x16x32_bf16(fa01, fb01, acc11, 0, 0, 0);
        acc00 = __builtin_amdgcn_mfma_f32_16x16x32_bf16(fa10, fb10, acc00, 0, 0, 0);
        acc01 = __builtin_amdgcn_mfma_f32_16x16x32_bf16(fa10, fb11, acc01, 0, 0, 0);
        acc10 = __builtin_amdgcn_mfma_f32_16x16x32_bf16(fa11, fb10, acc10, 0, 0, 0);
        acc11 = __builtin_amdgcn_mfma_f32_16x16x32_bf16(fa11, fb11, acc11, 0, 0, 0);
        // ---- issue stage kt+2 into nxt; counted wait leaves it in flight ----
        if (kt < 30) {
            STAGE(kt + 2, nxt);
            asm volatile("s_waitcnt vmcnt(4)" ::: "memory");
        } else {
            asm volatile("s_waitcnt vmcnt(0)" ::: "memory");
        }
        __builtin_amdgcn_sched_barrier(0);
        __builtin_amdgcn_s_barrier();
        __builtin_amdgcn_sched_barrier(0);
        cur = (cur == 2) ? 0 : cur + 1;
        nxt = (nxt == 2) ? 0 : nxt + 1;
    }
#undef STAGE

    // epilogue: store C fp32 (bias applied exactly in sim_s_kernel)
    f32x4 acc[2][2] = {{acc00, acc01}, {acc10, acc11}};
    #pragma unroll
    for (int mi = 0; mi < 2; ++mi)
        #pragma unroll
        for (int ni = 0; ni < 2; ++ni) {
            int col = nt * 64 + wc * 32 + ni * 16 + lrow;
            #pragma unroll
            for (int r = 0; r < 4; ++r) {
                int row = mt * 64 + wr * 32 + mi * 16 + lhi * 4 + r;
                Out[(size_t)row * 2048 + col] = acc[mi][ni][r];
            }
        }
}

// ---------------- kernel 2: sim[b,h] = (q+bq)·(k+bk) ; S[b][n] = kv·WvS + bvS ----------------
__global__ __launch_bounds__(256) void sim_s_kernel(
        const float* __restrict__ bq, const float* __restrict__ bkv,
        const float* __restrict__ kvin, unsigned char* __restrict__ ws) {
    int b = blockIdx.x, t = threadIdx.x;
    int w = t >> 6, l = t & 63;
    // --- sim part: wave w covers heads 4w..4w+3, lanes = d ---
    {
        const float* orow = (const float*)(ws + WS_OUT_OFF) + (size_t)b * 2048;
        float* sim = (float*)(ws + WS_SIM_OFF);
        #pragma unroll
        for (int hh = 0; hh < 4; ++hh) {
            int h = w * 4 + hh;
            float qv = orow[h * 64 + l]        + bq[h * 64 + l];
            float kv = orow[1024 + h * 64 + l] + bkv[h * 128 + l];
            float p = qv * kv;
            p += __shfl_xor(p, 1);  p += __shfl_xor(p, 2);
            p += __shfl_xor(p, 4);  p += __shfl_xor(p, 8);
            p += __shfl_xor(p, 16); p += __shfl_xor(p, 32);
            if (l == 0) sim[b * 16 + h] = p;
        }
    }
    // --- S part ---
    __shared__ float SW[4][16];
    int n = t & 15, g = t >> 4;
    const float* kvrow = kvin + (size_t)b * 2048;
    const float* wv = (const float*)(ws + WS_WVS_OFF);
    float p = 0.f;
    #pragma unroll 4
    for (int tt = 0; tt < 128; ++tt) {
        int c = g + (tt << 4);
        p = fmaf(kvrow[c], wv[c * 16 + n], p);
    }
    p += __shfl_xor(p, 16);
    p += __shfl_xor(p, 32);
    if (l < 16) SW[w][n] = p;
    __syncthreads();
    if (t < 16) {
        float sv = SW[0][t] + SW[1][t] + SW[2][t] + SW[3][t]
                 + ((const float*)(ws + WS_BVS_OFF))[t];
        ((float*)(ws + WS_S_OFF))[b * 16 + t] = sv;
    }
}

// ---------------- kernel 3: softmax, A-reduce, pooled, leaky, batchnorm, output ----------------
__global__ __launch_bounds__(1024) void final_kernel(
        const float* __restrict__ bn_w, const float* __restrict__ bn_b,
        const float* __restrict__ Wo, const float* __restrict__ bo,
        const unsigned char* __restrict__ ws, float* __restrict__ out) {
    int t = threadIdx.x;
    int w = t >> 6;
    int l = t & 63;
    __shared__ float Aw[16][16];
    __shared__ float Af[4][16];
    __shared__ float SWs[16][8];
    __shared__ float FS[8];
    __shared__ float sc[4], sh[4];

    float a16[16];
    {
        const float* srow = (const float*)(ws + WS_SIM_OFF) + (size_t)t * 16;
        float4 v0 = *(const float4*)(srow + 0);
        float4 v1 = *(const float4*)(srow + 4);
        float4 v2 = *(const float4*)(srow + 8);
        float4 v3 = *(const float4*)(srow + 12);
        a16[0]=v0.x; a16[1]=v0.y; a16[2]=v0.z; a16[3]=v0.w;
        a16[4]=v1.x; a16[5]=v1.y; a16[6]=v1.z; a16[7]=v1.w;
        a16[8]=v2.x; a16[9]=v2.y; a16[10]=v2.z; a16[11]=v2.w;
        a16[12]=v3.x; a16[13]=v3.y; a16[14]=v3.z; a16[15]=v3.w;
        float m = a16[0];
        #pragma unroll
        for (int n = 1; n < 16; ++n) m = fmaxf(m, a16[n]);
        float den = 0.f;
        #pragma unroll
        for (int n = 0; n < 16; ++n) { a16[n] = expf(a16[n] - m); den += a16[n]; }
        float inv = 1.f / den;
        #pragma unroll
        for (int n = 0; n < 16; ++n) a16[n] *= inv;
    }
    #pragma unroll
    for (int n = 0; n < 16; ++n) {
        float p = a16[n];
        p += __shfl_xor(p, 1);  p += __shfl_xor(p, 2);
        p += __shfl_xor(p, 4);  p += __shfl_xor(p, 8);
        p += __shfl_xor(p, 16); p += __shfl_xor(p, 32);
        a16[n] = p;
    }
    if (l == 0) {
        #pragma unroll
        for (int n = 0; n < 16; ++n) Aw[w][n] = a16[n];
    }
    __syncthreads();
    if (t < 64) {
        int f = t >> 4, n = t & 15;
        Af[f][n] = Aw[4*f][n] + Aw[4*f+1][n] + Aw[4*f+2][n] + Aw[4*f+3][n];
    }
    __syncthreads();

    float sv[16];
    {
        const float* srow = (const float*)(ws + WS_S_OFF) + (size_t)t * 16;
        float4 v0 = *(const float4*)(srow + 0);
        float4 v1 = *(const float4*)(srow + 4);
        float4 v2 = *(const float4*)(srow + 8);
        float4 v3 = *(const float4*)(srow + 12);
        sv[0]=v0.x; sv[1]=v0.y; sv[2]=v0.z; sv[3]=v0.w;
        sv[4]=v1.x; sv[5]=v1.y; sv[6]=v1.z; sv[7]=v1.w;
        sv[8]=v2.x; sv[9]=v2.y; sv[10]=v2.z; sv[11]=v2.w;
        sv[12]=v3.x; sv[13]=v3.y; sv[14]=v3.z; sv[15]=v3.w;
    }
    float x[4];
    #pragma unroll
    for (int f = 0; f < 4; ++f) {
        float p = 0.f;
        #pragma unroll
        for (int n = 0; n < 16; ++n) p = fmaf(Af[f][n], sv[n], p);
        p *= (1.f / 16384.f);
        x[f] = (p >= 0.f) ? p : SLOPE * p;
    }

    float st[8];
    #pragma unroll
    for (int f = 0; f < 4; ++f) { st[f] = x[f]; st[4 + f] = x[f] * x[f]; }
    #pragma unroll
    for (int j = 0; j < 8; ++j) {
        float p = st[j];
        p += __shfl_xor(p, 1);  p += __shfl_xor(p, 2);
        p += __shfl_xor(p, 4);  p += __shfl_xor(p, 8);
        p += __shfl_xor(p, 16); p += __shfl_xor(p, 32);
        st[j] = p;
    }
    if (l == 0) {
        #pragma unroll
        for (int j = 0; j < 8; ++j) SWs[w][j] = st[j];
    }
    __syncthreads();
    if (t < 8) {
        float p = 0.f;
        #pragma unroll
        for (int ww = 0; ww < 16; ++ww) p += SWs[ww][t];
        FS[t] = p;
    }
    __syncthreads();
    if (t < 4) {
        float mean = FS[t] * (1.f / 1024.f);
        float var  = FS[4 + t] * (1.f / 1024.f) - mean * mean;
        float s = bn_w[t] / sqrtf(var + EPS);
        sc[t] = s;
        sh[t] = bn_b[t] - mean * s;
    }
    __syncthreads();

    float o0 = bo[0], o1 = bo[1];
    #pragma unroll
    for (int f = 0; f < 4; ++f) {
        float xh = x[f] * sc[f] + sh[f];
        o0 = fmaf(xh, Wo[f], o0);
        o1 = fmaf(xh, Wo[4 + f], o1);
    }
    *(float2*)(out + (size_t)t * 2) = make_float2(o0, o1);
}

// ---------------- launch ----------------
extern "C" void kernel_launch(void* const* d_in, const int* in_sizes, int n_in,
                              void* d_out, int out_size, void* d_ws, size_t ws_size,
                              hipStream_t stream) {
    const float* q_input  = (const float*)d_in[0];
    const float* kv_input = (const float*)d_in[1];
    const float* Wq   = (const float*)d_in[2];
    const float* bq   = (const float*)d_in[3];
    const float* Wkv  = (const float*)d_in[4];
    const float* bkv  = (const float*)d_in[5];
    const float* bn_w = (const float*)d_in[6];
    const float* bn_b = (const float*)d_in[7];
    const float* Wo   = (const float*)d_in[8];
    const float* bo   = (const float*)d_in[9];
    float* out = (float*)d_out;
    unsigned char* ws = (unsigned char*)d_ws;

    hipLaunchKernelGGL(prep_kernel, dim3((PREP_END + 255) / 256), dim3(256), 0, stream,
                       q_input, kv_input, Wq, Wkv, bkv, ws);
    hipLaunchKernelGGL(gemm_qk_kernel, dim3(32, 16), dim3(256), 0, stream, ws);
    hipLaunchKernelGGL(sim_s_kernel, dim3(1024), dim3(256), 0, stream,
                       bq, bkv, kv_input, ws);
    hipLaunchKernelGGL(final_kernel, dim3(1), dim3(1024), 0, stream,
                       bn_w, bn_b, Wo, bo, ws, out);
}